// Round 1
// baseline (685.650 us; speedup 1.0000x reference)
//
#include <hip/hip_runtime.h>

#define NB 4096
#define NT 256
#define NC 64
#define NH 16
#define NS 10
#define NTO 255

__device__ __forceinline__ float fast_rcp(float x){
#if __has_builtin(__builtin_amdgcn_rcpf)
    return __builtin_amdgcn_rcpf(x);
#else
    return 1.0f/x;
#endif
}
__device__ __forceinline__ float fast_rsq(float x){
#if __has_builtin(__builtin_amdgcn_rsqf)
    return __builtin_amdgcn_rsqf(x);
#else
    return rsqrtf(x);
#endif
}
__device__ __forceinline__ float fsig(float x){
    return fast_rcp(1.0f + __expf(-x));
}
__device__ __forceinline__ float ftanh(float x){
    float e = __expf(2.0f*x);                 // inf for large x -> rcp -> 0 -> tanh=1 (correct)
    return fmaf(-2.0f, fast_rcp(e + 1.0f), 1.0f);
}

// lane layout: lane = g*16 + l; g = row-in-wave (4 rows/wave), l = hidden index (H=16)
__global__ __launch_bounds__(64, 1) void vpf_kernel(
    const float* __restrict__ states, const float* __restrict__ cov,
    const float* __restrict__ lng,    const float* __restrict__ lnb,
    const float* __restrict__ wx,     const float* __restrict__ wh,
    const float* __restrict__ rnb,    const float* __restrict__ d1w,
    const float* __restrict__ d1b,    const float* __restrict__ d2w,
    const float* __restrict__ d2b,    float* __restrict__ out)
{
    const int lane = threadIdx.x;
    const int g = lane >> 4, l = lane & 15;
    const int b = (blockIdx.x << 2) + g;

    __shared__ __align__(16) float buf[2][4*NC];   // double-buffered cov rows, 2 KB

    // ---- per-lane weight columns (column l) ----
    // fold LayerNorm gamma into wx:  gw[c] = gamma[c]*wx[c][l]
    float gw[NC]; float Gs = 0.f, bacc = 0.f;
    #pragma unroll
    for (int c = 0; c < NC; ++c) {
        float w = wx[c*NH + l];
        float t = lng[c] * w;
        gw[c] = t; Gs += t;
        bacc = fmaf(lnb[c], w, bacc);
    }
    const float bwb = bacc + rnb[l];               // beta@wx + rnn_b, fused bias
    float whc[NH], d1c[NH], d2c[NH];
    #pragma unroll
    for (int k = 0; k < NH; ++k) {
        whc[k] = wh[k*NH + l];
        d1c[k] = d1w[k*NH + l];
        d2c[k] = d2w[k*NH + l];
    }
    const float d1bl = d1b[l], d2bl = d2b[l];

    // ---- cash-budget state (replicated on all 16 lanes of the group) ----
    float s0,s1,s2,s3,s4,s5,s6,s7,s8,s9;
    { const float* sp = states + (size_t)b*NT*NS;  // states_seq[b][0][*]
      s0=sp[0];s1=sp[1];s2=sp[2];s3=sp[3];s4=sp[4];
      s5=sp[5];s6=sp[6];s7=sp[7];s8=sp[8];s9=sp[9]; }

    float* spo = out + (size_t)b*NTO*NS + l;                         // states_pred[b][0][l]
    float* ipo = out + (size_t)NB*NTO*NS + (size_t)b*NTO*7 + l;      // is_pred[b][0][l]

    // ---- covariate streaming: 2-deep register prefetch -> LDS double buffer ----
    const float4* gp = (const float4*)(cov + (size_t)b*NT*NC) + l;   // gp[t*16] = cov[b][t][l*4..l*4+3]
    float4 v0 = gp[0];
    float4 v1 = gp[16];
    float4 ra = gp[32];       // data(t+2) at loop entry
    float4 rb = gp[48];       // data(t+3)
    ((float4*)buf[0])[lane] = v0;
    ((float4*)buf[1])[lane] = v1;
    __syncthreads();

    auto compute_xw = [&](const float* bp) -> float {
        const float4* row = (const float4*)(bp + g*NC);
        // LN moments from own slice + 16-lane butterfly
        float4 ov = row[l];
        float ss = (ov.x+ov.y)+(ov.z+ov.w);
        float sq = fmaf(ov.x,ov.x, fmaf(ov.y,ov.y, fmaf(ov.z,ov.z, ov.w*ov.w)));
        #pragma unroll
        for (int m = 1; m < 16; m <<= 1) {
            ss += __shfl_xor(ss, m);
            sq += __shfl_xor(sq, m);
        }
        float mu  = ss * (1.0f/64.0f);
        float var = fmaf(-mu, mu, sq * (1.0f/64.0f));
        float rs  = fast_rsq(var + 0.001f);
        // dot(cov_row, gw) -- broadcast ds_read_b128 within the group, 4 accumulators
        float a0=0.f, a1=0.f, a2=0.f, a3=0.f;
        #pragma unroll
        for (int c = 0; c < 16; ++c) {
            float4 v = row[c];
            a0 = fmaf(v.x, gw[4*c+0], a0);
            a1 = fmaf(v.y, gw[4*c+1], a1);
            a2 = fmaf(v.z, gw[4*c+2], a2);
            a3 = fmaf(v.w, gw[4*c+3], a3);
        }
        float dot = (a0+a1)+(a2+a3);
        return fmaf(rs, fmaf(-mu, Gs, dot), bwb);
    };

    float xw = compute_xw(buf[0]);    // xw(t=0)
    float hrep[NH];
    #pragma unroll
    for (int j = 0; j < NH; ++j) hrep[j] = 0.f;
    const int base4 = (lane & 48) << 2;     // byte index of group's lane 0 for ds_bpermute

    #pragma unroll 1
    for (int t = 0; t < NT; ++t) {
        // stage data(t+2) into the buffer freed last iteration; refill register pipe
        if (t < NT-2) { ((float4*)buf[t&1])[lane] = ra; ra = rb; }
        if (t < NT-4) { rb = gp[(t+4)*16]; }
        // compute next timestep's xw (independent work -> overlaps recurrence chain)
        float xwn = 0.f;
        if (t < NT-1) xwn = compute_xw(buf[(t+1)&1]);

        // ---- RNN step t ----
        float a0 = xw, a1 = 0.f;
        #pragma unroll
        for (int k = 0; k < NH; k += 2) {
            a0 = fmaf(hrep[k],   whc[k],   a0);
            a1 = fmaf(hrep[k+1], whc[k+1], a1);
        }
        float hn = ftanh(a0 + a1);
        int hni = __float_as_int(hn);
        #pragma unroll
        for (int j = 0; j < NH; ++j)
            hrep[j] = __int_as_float(__builtin_amdgcn_ds_bpermute(base4 + 4*j, hni));

        if (t >= 1) {
            // ---- driver MLP ----
            float b0 = d1bl, b1 = 0.f;
            #pragma unroll
            for (int k = 0; k < NH; k += 2) {
                b0 = fmaf(hrep[k],   d1c[k],   b0);
                b1 = fmaf(hrep[k+1], d1c[k+1], b1);
            }
            float t1 = ftanh(b0 + b1);
            int t1i = __float_as_int(t1);
            float t1rep[NH];
            #pragma unroll
            for (int j = 0; j < NH; ++j)
                t1rep[j] = __int_as_float(__builtin_amdgcn_ds_bpermute(base4 + 4*j, t1i));
            float c0 = d2bl, c1 = 0.f;
            #pragma unroll
            for (int k = 0; k < NH; k += 2) {
                c0 = fmaf(t1rep[k],   d2c[k],   c0);
                c1 = fmaf(t1rep[k+1], d2c[k+1], c1);
            }
            float dv = c0 + c1;                 // driver component l
            int dvi = __float_as_int(dv);
            float dd[10];
            #pragma unroll
            for (int j = 0; j < 10; ++j)
                dd[j] = __int_as_float(__builtin_amdgcn_ds_bpermute(base4 + 4*j, dvi));

            // ---- cash budget (replicated across the 16 lanes) ----
            float gg    = 0.2f  * ftanh(dd[0]);
            float cogsm = fsig(dd[1]);
            float opexm = 0.5f  * fsig(dd[2]);
            float depr  = 0.1f  * fsig(dd[3]);
            float capr  = 0.2f  * fsig(dd[4]);
            float dso   = fsig(dd[5]);
            float dio   = fsig(dd[6]);
            float dpo   = fsig(dd[7]);
            float taxr  = 0.35f * fsig(dd[8]);
            float intr  = 0.1f  * fsig(dd[9]);

            float rev   = fmaf(s0, gg, s0);
            float cogs  = cogsm * rev;
            float opex  = opexm * rev;
            float dep   = depr * s4;
            float inte  = intr * s6;
            float ebt   = (((rev - cogs) - opex) - dep) - inte;
            float tax   = taxr * fmaxf(ebt, 0.0f);
            float ni    = ebt - tax;
            float arn   = dso * rev;
            float invn  = dio * cogs;
            float apn   = dpo * cogs;
            float capex = capr * rev;
            float ppen  = (s4 + capex) - dep;
            float cashn = (((((s1 + ni) + dep) - capex) - (arn - s2)) - (invn - s3)) + (apn - s5);
            float ren   = s8 + ni;

            s0=rev; s1=cashn; s2=arn; s3=invn; s4=ppen; s5=apn; s8=ren;

            // lane-select store: lane l writes element l
            float sv = (l==0)?rev:(l==1)?cashn:(l==2)?arn:(l==3)?invn:(l==4)?ppen:
                       (l==5)?apn:(l==6)?s6:(l==7)?s7:(l==8)?ren:s9;
            float iv = (l==0)?rev:(l==1)?cogs:(l==2)?opex:(l==3)?dep:(l==4)?inte:(l==5)?tax:ni;
            if (l < NS) *spo = sv;
            if (l < 7)  *ipo = iv;
            spo += NS; ipo += 7;
        }
        xw = xwn;
        __syncthreads();   // publish this iteration's ds_write for next iteration's reads
    }
}

extern "C" void kernel_launch(void* const* d_in, const int* in_sizes, int n_in,
                              void* d_out, int out_size, void* d_ws, size_t ws_size,
                              hipStream_t stream) {
    (void)in_sizes; (void)n_in; (void)d_ws; (void)ws_size; (void)out_size;
    vpf_kernel<<<NB/4, 64, 0, stream>>>(
        (const float*)d_in[0],  // states_seq
        (const float*)d_in[1],  // covariates_seq
        (const float*)d_in[2],  // ln_gamma
        (const float*)d_in[3],  // ln_beta
        (const float*)d_in[4],  // rnn_wx
        (const float*)d_in[5],  // rnn_wh
        (const float*)d_in[6],  // rnn_b
        (const float*)d_in[7],  // d1_w
        (const float*)d_in[8],  // d1_b
        (const float*)d_in[9],  // d2_w
        (const float*)d_in[10], // d2_b
        (float*)d_out);
}

// Round 2
// 669.517 us; speedup vs baseline: 1.0241x; 1.0241x over previous
//
#include <hip/hip_runtime.h>
#include <hip/hip_fp16.h>

#define NB 4096
#define NT 256
#define NC 64
#define NH 16
#define NS 10
#define NTO 255

__device__ __forceinline__ float fast_rcp(float x){
#if __has_builtin(__builtin_amdgcn_rcpf)
    return __builtin_amdgcn_rcpf(x);
#else
    return 1.0f/x;
#endif
}
__device__ __forceinline__ float fast_rsq(float x){
#if __has_builtin(__builtin_amdgcn_rsqf)
    return __builtin_amdgcn_rsqf(x);
#else
    return rsqrtf(x);
#endif
}
__device__ __forceinline__ float fsig(float x){
    return fast_rcp(1.0f + __expf(-x));
}
__device__ __forceinline__ float ftanh(float x){
    float e = __expf(2.0f*x);                 // inf for large x -> rcp -> 0 -> tanh=1 (correct)
    return fmaf(-2.0f, fast_rcp(e + 1.0f), 1.0f);
}

// lane layout: lane = g*16 + l; g = row-in-wave (4 batches/wave), l = hidden index (H=16)
// Block = exactly one wave => NO BARRIERS ANYWHERE: LDS ops from a single wave
// execute in order (wave-synchronous programming); compiler handles lgkmcnt.
__global__ __launch_bounds__(64, 1) void vpf_kernel(
    const float* __restrict__ states, const float* __restrict__ cov,
    const float* __restrict__ lng,    const float* __restrict__ lnb,
    const float* __restrict__ wx,     const float* __restrict__ wh,
    const float* __restrict__ rnb,    const float* __restrict__ d1w,
    const float* __restrict__ d1b,    const float* __restrict__ d2w,
    const float* __restrict__ d2b,    float* __restrict__ out)
{
    const int lane = threadIdx.x;
    const int g = lane >> 4, l = lane & 15;
    const int b = (blockIdx.x << 2) + g;

    // LDS budget: 32K + 2K + 3*256B = 35.6 KB -> 4 blocks/CU fits in 160 KB.
    __shared__ __half2 xws[128*64];                 // xw[t-pair][lane], fp16x2, 32 KB
    __shared__ __align__(16) float stg[2][4*NC];    // cov row staging dbuf, 2 KB
    __shared__ __align__(16) float hb[64];          // h broadcast
    __shared__ __align__(16) float tb[64];          // tanh-layer broadcast
    __shared__ __align__(16) float db[64];          // activated-driver broadcast

    // ---- per-lane weight columns (column l) ----
    float gw[NC]; float Gs = 0.f, bacc = 0.f;
    #pragma unroll
    for (int c = 0; c < NC; ++c) {
        float w = wx[c*NH + l];
        float t = lng[c] * w;
        gw[c] = t; Gs += t;
        bacc = fmaf(lnb[c], w, bacc);
    }
    const float bwb = bacc + rnb[l];               // beta@wx + rnn_b, fused bias
    float whc[NH], d1c[NH], d2c[NH];
    #pragma unroll
    for (int k = 0; k < NH; ++k) {
        whc[k] = wh[k*NH + l];
        d1c[k] = d1w[k*NH + l];
        d2c[k] = d2w[k*NH + l];
    }
    const float d1bl = d1b[l], d2bl = d2b[l];
    // per-lane driver activation: act = A*sigmoid(B*x) + C
    // lane0: 0.2*tanh(x) = 0.4*sig(2x) - 0.2 ; others scaled sigmoids
    const float Aa = (l==0)?0.4f:(l==2)?0.5f:(l==3)?0.1f:(l==4)?0.2f:(l==8)?0.35f:(l==9)?0.1f:1.0f;
    const float Ba = (l==0)?2.0f:1.0f;
    const float Ca = (l==0)?-0.2f:0.0f;

    auto compute_xw = [&](const float* bp) -> float {
        const float4* row = (const float4*)(bp + g*NC);
        float4 ov = row[l];
        float ss = (ov.x+ov.y)+(ov.z+ov.w);
        float sq = fmaf(ov.x,ov.x, fmaf(ov.y,ov.y, fmaf(ov.z,ov.z, ov.w*ov.w)));
        #pragma unroll
        for (int m = 1; m < 16; m <<= 1) {
            ss += __shfl_xor(ss, m);
            sq += __shfl_xor(sq, m);
        }
        float mu  = ss * (1.0f/64.0f);
        float var = fmaf(-mu, mu, sq * (1.0f/64.0f));
        float rs  = fast_rsq(var + 0.001f);
        float a0=0.f, a1=0.f, a2=0.f, a3=0.f;
        #pragma unroll
        for (int c = 0; c < 16; ++c) {
            float4 v = row[c];
            a0 = fmaf(v.x, gw[4*c+0], a0);
            a1 = fmaf(v.y, gw[4*c+1], a1);
            a2 = fmaf(v.z, gw[4*c+2], a2);
            a3 = fmaf(v.w, gw[4*c+3], a3);
        }
        float dot = (a0+a1)+(a2+a3);
        return fmaf(rs, fmaf(-mu, Gs, dot), bwb);
    };

    // ================= PHASE 1: xw for all 256 timesteps =================
    // 6-deep pipeline: LDS holds rows p,p+1; regs hold p+2..p+5; loads issued to p+5.
    const float4* gp = (const float4*)(cov + (size_t)b*NT*NC) + l;
    float4 ra, rb2, rc, rd;
    {
        float4 v0 = gp[0], v1 = gp[16];
        ra = gp[32]; rb2 = gp[48]; rc = gp[64]; rd = gp[80];
        ((float4*)stg[0])[lane] = v0;
        ((float4*)stg[1])[lane] = v1;
    }
    float xw_even = 0.f;
    #pragma unroll 2
    for (int p = 0; p < NT; ++p) {
        float xwv = compute_xw(stg[p&1]);          // reads slot (in-order DS)
        if (p < NT-2) ((float4*)stg[p&1])[lane] = ra;   // refill after reads
        ra = rb2; rb2 = rc; rc = rd;
        if (p < NT-6) rd = gp[(p+6)*16];
        if (p & 1) {
            xws[(p>>1)*64 + lane] = __halves2half2(__float2half(xw_even), __float2half(xwv));
        } else {
            xw_even = xwv;
        }
    }

    // ================= PHASE 2: the scan =================
    float s0,s1,s2,s3,s4,s5,s6,s7,s8,s9;
    { const float* sp = states + (size_t)b*NT*NS;
      s0=sp[0];s1=sp[1];s2=sp[2];s3=sp[3];s4=sp[4];
      s5=sp[5];s6=sp[6];s7=sp[7];s8=sp[8];s9=sp[9]; }

    float* spo = out + (size_t)b*NTO*NS + l;
    float* ipo = out + (size_t)NB*NTO*NS + (size_t)b*NTO*7 + l;

    float hrep[NH];
    #pragma unroll
    for (int j = 0; j < NH; ++j) hrep[j] = 0.f;

    __half2 xu = xws[lane];       // pair for t=0,1
    __half2 xun = xu;

    #pragma unroll 2
    for (int t = 0; t < NT; ++t) {
        float xwv;
        if ((t & 1) == 0) {
            xwv = __low2float(xu);
            if (t + 2 < NT) xun = xws[((t+2)>>1)*64 + lane];   // prefetch next pair
        } else {
            xwv = __high2float(xu);
            xu = xun;
        }

        // ---- RNN step t ----
        float a0 = xwv, a1 = 0.f;
        #pragma unroll
        for (int k = 0; k < NH; k += 2) {
            a0 = fmaf(hrep[k],   whc[k],   a0);
            a1 = fmaf(hrep[k+1], whc[k+1], a1);
        }
        float hn = ftanh(a0 + a1);
        hb[lane] = hn;                              // ds_write_b32
        { const float4* hp = ((const float4*)hb) + g*4;
          float4 h0 = hp[0], h1 = hp[1], h2 = hp[2], h3 = hp[3];
          hrep[0]=h0.x; hrep[1]=h0.y; hrep[2]=h0.z; hrep[3]=h0.w;
          hrep[4]=h1.x; hrep[5]=h1.y; hrep[6]=h1.z; hrep[7]=h1.w;
          hrep[8]=h2.x; hrep[9]=h2.y; hrep[10]=h2.z; hrep[11]=h2.w;
          hrep[12]=h3.x; hrep[13]=h3.y; hrep[14]=h3.z; hrep[15]=h3.w; }

        if (t >= 1) {
            // ---- driver MLP ----
            float b0 = d1bl, b1 = 0.f;
            #pragma unroll
            for (int k = 0; k < NH; k += 2) {
                b0 = fmaf(hrep[k],   d1c[k],   b0);
                b1 = fmaf(hrep[k+1], d1c[k+1], b1);
            }
            float t1 = ftanh(b0 + b1);
            tb[lane] = t1;
            float tr[NH];
            { const float4* tp = ((const float4*)tb) + g*4;
              float4 u0 = tp[0], u1 = tp[1], u2 = tp[2], u3 = tp[3];
              tr[0]=u0.x; tr[1]=u0.y; tr[2]=u0.z; tr[3]=u0.w;
              tr[4]=u1.x; tr[5]=u1.y; tr[6]=u1.z; tr[7]=u1.w;
              tr[8]=u2.x; tr[9]=u2.y; tr[10]=u2.z; tr[11]=u2.w;
              tr[12]=u3.x; tr[13]=u3.y; tr[14]=u3.z; tr[15]=u3.w; }
            float c0 = d2bl, c1 = 0.f;
            #pragma unroll
            for (int k = 0; k < NH; k += 2) {
                c0 = fmaf(tr[k],   d2c[k],   c0);
                c1 = fmaf(tr[k+1], d2c[k+1], c1);
            }
            float dv = c0 + c1;                      // raw driver component l
            float act = fmaf(Aa, fsig(Ba * dv), Ca); // lane-local activation
            db[lane] = act;
            float dd0,dd1,dd2,dd3,dd4,dd5,dd6,dd7,dd8,dd9;
            { const float4* dp = ((const float4*)db) + g*4;
              float4 w0 = dp[0], w1 = dp[1], w2 = dp[2];
              dd0=w0.x; dd1=w0.y; dd2=w0.z; dd3=w0.w;
              dd4=w1.x; dd5=w1.y; dd6=w1.z; dd7=w1.w;
              dd8=w2.x; dd9=w2.y; }

            // ---- cash budget (replicated across the 16 lanes) ----
            float rev   = fmaf(s0, dd0, s0);
            float cogs  = dd1 * rev;
            float opex  = dd2 * rev;
            float dep   = dd3 * s4;
            float inte  = dd9 * s6;
            float ebt   = (((rev - cogs) - opex) - dep) - inte;
            float tax   = dd8 * fmaxf(ebt, 0.0f);
            float ni    = ebt - tax;
            float arn   = dd5 * rev;
            float invn  = dd6 * cogs;
            float apn   = dd7 * cogs;
            float capex = dd4 * rev;
            float ppen  = (s4 + capex) - dep;
            float cashn = (((((s1 + ni) + dep) - capex) - (arn - s2)) - (invn - s3)) + (apn - s5);
            float ren   = s8 + ni;

            s0=rev; s1=cashn; s2=arn; s3=invn; s4=ppen; s5=apn; s8=ren;

            float sv = (l==0)?rev:(l==1)?cashn:(l==2)?arn:(l==3)?invn:(l==4)?ppen:
                       (l==5)?apn:(l==6)?s6:(l==7)?s7:(l==8)?ren:s9;
            float iv = (l==0)?rev:(l==1)?cogs:(l==2)?opex:(l==3)?dep:(l==4)?inte:(l==5)?tax:ni;
            if (l < NS) *spo = sv;
            if (l < 7)  *ipo = iv;
            spo += NS; ipo += 7;
        }
    }
}

extern "C" void kernel_launch(void* const* d_in, const int* in_sizes, int n_in,
                              void* d_out, int out_size, void* d_ws, size_t ws_size,
                              hipStream_t stream) {
    (void)in_sizes; (void)n_in; (void)d_ws; (void)ws_size; (void)out_size;
    vpf_kernel<<<NB/4, 64, 0, stream>>>(
        (const float*)d_in[0],  // states_seq
        (const float*)d_in[1],  // covariates_seq
        (const float*)d_in[2],  // ln_gamma
        (const float*)d_in[3],  // ln_beta
        (const float*)d_in[4],  // rnn_wx
        (const float*)d_in[5],  // rnn_wh
        (const float*)d_in[6],  // rnn_b
        (const float*)d_in[7],  // d1_w
        (const float*)d_in[8],  // d1_b
        (const float*)d_in[9],  // d2_w
        (const float*)d_in[10], // d2_b
        (float*)d_out);
}

// Round 3
// 598.617 us; speedup vs baseline: 1.1454x; 1.1184x over previous
//
#include <hip/hip_runtime.h>
#include <hip/hip_fp16.h>

#define NB 4096
#define NT 256
#define NC 64
#define NH 16
#define NS 10
#define NTO 255

__device__ __forceinline__ float fast_rcp(float x){ return __builtin_amdgcn_rcpf(x); }
__device__ __forceinline__ float fast_rsq(float x){ return __builtin_amdgcn_rsqf(x); }
__device__ __forceinline__ float fsig(float x){ return fast_rcp(1.0f + __expf(-x)); }
__device__ __forceinline__ float ftanh(float x){
    float e = __expf(2.0f*x);
    return fmaf(-2.0f, fast_rcp(e + 1.0f), 1.0f);
}

// row_ror:R within each 16-lane row: lane l receives lane (l-R)&15's value. VALU pipe, no LDS.
template<int R>
__device__ __forceinline__ float rotf(float x){
    return __int_as_float(__builtin_amdgcn_update_dpp(
        0, __float_as_int(x), 0x120 + R, 0xF, 0xF, true));
}
// butterfly sum over the 16-lane row, result broadcast to all 16 lanes
__device__ __forceinline__ float row_bcast_sum(float x){
    x += rotf<8>(x);
    x += rotf<4>(x);
    x += rotf<2>(x);
    x += rotf<1>(x);
    return x;
}
// acc + sum_k v_k * W[k][l], v distributed one element/lane, w[r] = W[(l-r)&15][l]
__device__ __forceinline__ float rotdot16(float v, const float* w, float acc){
    float a1 = 0.f;
    acc = fmaf(v,          w[0],  acc);
    a1  = fmaf(rotf<1>(v), w[1],  a1);
    acc = fmaf(rotf<2>(v), w[2],  acc);
    a1  = fmaf(rotf<3>(v), w[3],  a1);
    acc = fmaf(rotf<4>(v), w[4],  acc);
    a1  = fmaf(rotf<5>(v), w[5],  a1);
    acc = fmaf(rotf<6>(v), w[6],  acc);
    a1  = fmaf(rotf<7>(v), w[7],  a1);
    acc = fmaf(rotf<8>(v), w[8],  acc);
    a1  = fmaf(rotf<9>(v), w[9],  a1);
    acc = fmaf(rotf<10>(v),w[10], acc);
    a1  = fmaf(rotf<11>(v),w[11], a1);
    acc = fmaf(rotf<12>(v),w[12], acc);
    a1  = fmaf(rotf<13>(v),w[13], a1);
    acc = fmaf(rotf<14>(v),w[14], acc);
    a1  = fmaf(rotf<15>(v),w[15], a1);
    return acc + a1;
}

// ===================== K1: xw = LN(cov) @ (gamma-folded wx) + (beta@wx + rnn_b) =====================
// One wave per batch (4096 waves, 16/CU). Lane = g*16+l: g = t-subindex (4 t/iter), l = element-quarter.
// Zero LDS: stats via DPP reduce, dot via DPP rotation-systolic. Output fp16 ws[b][l][t].
__global__ __launch_bounds__(256, 4) void xw_kernel(
    const float* __restrict__ cov, const float* __restrict__ lng,
    const float* __restrict__ lnb, const float* __restrict__ wx,
    const float* __restrict__ rnb, __half* __restrict__ xws)
{
    const int wid  = threadIdx.x >> 6;
    const int lane = threadIdx.x & 63;
    const int g = lane >> 4, l = lane & 15;
    const int b = (blockIdx.x << 2) + wid;

    // rotated gamma-folded weights: gwr[4r+j] = lng[c]*wx[c][l], c = 4*((l-r)&15)+j
    float gwr[64];
    #pragma unroll
    for (int r = 0; r < 16; ++r) {
        int c0 = 4 * ((l - r) & 15);
        #pragma unroll
        for (int j = 0; j < 4; ++j)
            gwr[4*r+j] = lng[c0+j] * wx[(c0+j)*NH + l];
    }
    float bwb = rnb[l];
    #pragma unroll
    for (int c = 0; c < NC; ++c) bwb = fmaf(lnb[c], wx[c*NH + l], bwb);

    const float4* gp = (const float4*)cov + (size_t)b*NT*16 + g*16 + l;  // advance 64/iter
    __half* op = xws + ((size_t)b*16 + l)*NT + g;                        // advance 4/iter

    float4 cur = gp[0];
    float4 nxt = gp[64];
    #pragma unroll 2
    for (int it = 0; it < 64; ++it) {
        float4 x = cur;
        cur = nxt;
        if (it < 62) nxt = gp[(size_t)(it+2)*64];
        // LN stats over this row's 64 elements (16 lanes x 4)
        float ss = (x.x + x.y) + (x.z + x.w);
        float sq = fmaf(x.x,x.x, fmaf(x.y,x.y, fmaf(x.z,x.z, x.w*x.w)));
        ss = row_bcast_sum(ss);
        sq = row_bcast_sum(sq);
        float mu  = ss * (1.0f/64.0f);
        float var = fmaf(-mu, mu, sq * (1.0f/64.0f));
        float rs  = fast_rsq(var + 0.001f);
        float nmu = -mu * rs;
        float x0 = fmaf(x.x, rs, nmu), x1 = fmaf(x.y, rs, nmu);
        float x2 = fmaf(x.z, rs, nmu), x3 = fmaf(x.w, rs, nmu);
        // rotation-systolic dot over all 64 elements
        float a0 = bwb, a1 = 0.f, a2 = 0.f, a3 = 0.f;
        a0 = fmaf(x0, gwr[0], a0); a1 = fmaf(x1, gwr[1], a1);
        a2 = fmaf(x2, gwr[2], a2); a3 = fmaf(x3, gwr[3], a3);
#define ROTSTEP(R) { float r0=rotf<R>(x0), r1=rotf<R>(x1), r2=rotf<R>(x2), r3=rotf<R>(x3); \
        a0=fmaf(r0,gwr[4*R+0],a0); a1=fmaf(r1,gwr[4*R+1],a1); \
        a2=fmaf(r2,gwr[4*R+2],a2); a3=fmaf(r3,gwr[4*R+3],a3); }
        ROTSTEP(1)  ROTSTEP(2)  ROTSTEP(3)  ROTSTEP(4)  ROTSTEP(5)
        ROTSTEP(6)  ROTSTEP(7)  ROTSTEP(8)  ROTSTEP(9)  ROTSTEP(10)
        ROTSTEP(11) ROTSTEP(12) ROTSTEP(13) ROTSTEP(14) ROTSTEP(15)
#undef ROTSTEP
        float xw = (a0+a1)+(a2+a3);
        op[it*4] = __float2half(xw);
    }
}

// ===================== K2: the two sequential scans =====================
// 1024 blocks x 1 wave; lane = g*16+l, g = batch-in-wave, l = hidden index.
// h stays DISTRIBUTED (lane l owns h_l); all matvecs via DPP rotation. One LDS
// broadcast round per step (activated drivers). xw streamed from ws.
__global__ __launch_bounds__(64, 1) void scan_kernel(
    const float* __restrict__ states, const __half* __restrict__ xws,
    const float* __restrict__ wh,     const float* __restrict__ d1w,
    const float* __restrict__ d1b,    const float* __restrict__ d2w,
    const float* __restrict__ d2b,    float* __restrict__ out)
{
    const int lane = threadIdx.x;
    const int g = lane >> 4, l = lane & 15;
    const int b = (blockIdx.x << 2) + g;

    __shared__ __align__(16) float db[64];   // activated-driver broadcast, 256 B

    // rotated weight columns: w[r] = W[(l-r)&15][l]
    float whr[NH], d1r[NH], d2r[NH];
    #pragma unroll
    for (int r = 0; r < NH; ++r) {
        int src = (l - r) & 15;
        whr[r] = wh[src*NH + l];
        d1r[r] = d1w[src*NH + l];
        d2r[r] = d2w[src*NH + l];
    }
    const float d1bl = d1b[l], d2bl = d2b[l];
    // per-lane driver activation: act = A*sigmoid(B*x) + C  (lane0: 0.2*tanh via sig)
    const float Aa = (l==0)?0.4f:(l==2)?0.5f:(l==3)?0.1f:(l==4)?0.2f:(l==8)?0.35f:(l==9)?0.1f:1.0f;
    const float Ba = (l==0)?2.0f:1.0f;
    const float Ca = (l==0)?-0.2f:0.0f;

    float s0,s1,s2,s3,s4,s5,s6,s7,s8,s9;
    { const float* sp = states + (size_t)b*NT*NS;
      s0=sp[0];s1=sp[1];s2=sp[2];s3=sp[3];s4=sp[4];
      s5=sp[5];s6=sp[6];s7=sp[7];s8=sp[8];s9=sp[9]; }

    float* spo = out + (size_t)b*NTO*NS + l;
    float* ipo = out + (size_t)NB*NTO*NS + (size_t)b*NTO*7 + l;

    // per-lane xw time-series, contiguous fp16: 4 timesteps per ushort4, 2-deep prefetch
    const ushort4* xp = (const ushort4*)(xws + ((size_t)b*16 + l)*NT);
    ushort4 xa = xp[0], xb = xp[1];

    float h = 0.f;
    #pragma unroll 1
    for (int tt = 0; tt < 64; ++tt) {
        ushort4 xc = xa; xa = xb;
        if (tt < 62) xb = xp[tt+2];
        #pragma unroll
        for (int u = 0; u < 4; ++u) {
            const int t = tt*4 + u;
            float xwv = __half2float(__ushort_as_half(u==0?xc.x:u==1?xc.y:u==2?xc.z:xc.w));
            // RNN: h = tanh(xw + h @ wh)
            h = ftanh(rotdot16(h, whr, xwv));
            if (t > 0) {
                // driver MLP, all rotation-systolic
                float t1  = ftanh(rotdot16(h, d1r, d1bl));
                float dv  = rotdot16(t1, d2r, d2bl);
                float act = fmaf(Aa, fsig(Ba * dv), Ca);
                db[lane] = act;                                   // 1 ds_write_b32
                float4 w0 = *((const float4*)db + g*4);           // dd0..3
                float4 w1 = *((const float4*)db + g*4 + 1);       // dd4..7
                float2 w2 = *((const float2*)(db + g*16 + 8));    // dd8,9

                float rev   = fmaf(s0, w0.x, s0);
                float cogs  = w0.y * rev;
                float opex  = w0.z * rev;
                float dep   = w0.w * s4;
                float inte  = w2.y * s6;
                float ebt   = (((rev - cogs) - opex) - dep) - inte;
                float tax   = w2.x * fmaxf(ebt, 0.0f);
                float ni    = ebt - tax;
                float arn   = w1.y * rev;
                float invn  = w1.z * cogs;
                float apn   = w1.w * cogs;
                float capex = w1.x * rev;
                float ppen  = (s4 + capex) - dep;
                float cashn = (((((s1 + ni) + dep) - capex) - (arn - s2)) - (invn - s3)) + (apn - s5);
                float ren   = s8 + ni;

                s0=rev; s1=cashn; s2=arn; s3=invn; s4=ppen; s5=apn; s8=ren;

                float sv = (l==0)?rev:(l==1)?cashn:(l==2)?arn:(l==3)?invn:(l==4)?ppen:
                           (l==5)?apn:(l==6)?s6:(l==7)?s7:(l==8)?ren:s9;
                float iv = (l==0)?rev:(l==1)?cogs:(l==2)?opex:(l==3)?dep:(l==4)?inte:(l==5)?tax:ni;
                if (l < NS) *spo = sv;
                if (l < 7)  *ipo = iv;
                spo += NS; ipo += 7;
            }
        }
    }
}

extern "C" void kernel_launch(void* const* d_in, const int* in_sizes, int n_in,
                              void* d_out, int out_size, void* d_ws, size_t ws_size,
                              hipStream_t stream) {
    (void)in_sizes; (void)n_in; (void)ws_size; (void)out_size;
    __half* xws = (__half*)d_ws;   // 4096*16*256 fp16 = 33.5 MB
    xw_kernel<<<NB/4, 256, 0, stream>>>(
        (const float*)d_in[1],  // covariates_seq
        (const float*)d_in[2],  // ln_gamma
        (const float*)d_in[3],  // ln_beta
        (const float*)d_in[4],  // rnn_wx
        (const float*)d_in[6],  // rnn_b
        xws);
    scan_kernel<<<NB/4, 64, 0, stream>>>(
        (const float*)d_in[0],  // states_seq
        xws,
        (const float*)d_in[5],  // rnn_wh
        (const float*)d_in[7],  // d1_w
        (const float*)d_in[8],  // d1_b
        (const float*)d_in[9],  // d2_w
        (const float*)d_in[10], // d2_b
        (float*)d_out);
}